// Round 9
// baseline (225.042 us; speedup 1.0000x reference)
//
#include <hip/hip_runtime.h>
#include <hip/hip_bf16.h>

// MetaAdaptiveFusion: B=32, N=2048, H=256, F=8, NH=8, dh=32, 3 meta steps.
// Inputs: fp32 buffers holding bf16-quantized values -> bf16 casts of INPUTS are
// LOSSLESS. Computed activations (qh, w, ctx, ho, e*cw) are hi/lo-split
// compensated bf16; residual carries stay fp32. Output fp32.
//
// R16: (a) k4 reverted to 256-block geometry (R15's 16-way split doubled merge
// atomics + halved amortization: 49us vs <41). (b) k4+k5 merged into ONE kernel
// via split-K "last-block ticket": each k4 block after its W/l atomics does
// threadfence + block-sync + one agent-scope ACQ_REL fetch_add on its b-tile
// counter; the last 8 of 128 blocks each run dev_k5(f) in-place. Removes one
// dispatch boundary (~15-20us of the ~80us/iter gap time) without R14's
// cooperative grid-sync tax. Visibility: wbuf/lbuf written ONLY via device-scope
// atomics (cross-XCD correctness proven R12-R15); reader does acquire RMW +
// threadfence, L2 holds no stale wbuf lines (no plain wbuf accesses in-kernel).
// Math bit-identical to R13 -> absmax unchanged (failure would be loud).
// Pipeline: k1_all (k1 + metaT + zero wbuf/lbuf/out/tickets); k4k5_fused.
// Fragment layouts per verified gfx950 conventions (A: m=lane&15,
// k=(lane>>4)*8+j ; B: n=lane&15 same k ; D: col=lane&15, row=(lane>>4)*4+reg).

#define B_ 32
#define N_ 2048
#define H_ 256
#define F_ 8
#define FH_ 64
#define NCH_ 8    // 8 n-split blocks of 256 docs
#define NCHK_ 4   // chunks of 64 n per block

typedef unsigned short u16;
typedef __attribute__((ext_vector_type(8))) short bf16x8;   // 8 bf16 (4 VGPRs)
typedef __attribute__((ext_vector_type(4))) float f32x4;
#define MFMA(a, b, c) __builtin_amdgcn_mfma_f32_16x16x32_bf16((a), (b), (c), 0, 0, 0)

__device__ __forceinline__ u16 f2b(float x) {   // fp32 -> bf16 bits, RNE
  unsigned u = __builtin_bit_cast(unsigned, x);
  return (u16)((u + 0x7fffu + ((u >> 16) & 1u)) >> 16);
}
__device__ __forceinline__ float b2f(u16 h) {
  unsigned u = ((unsigned)h) << 16;
  return __builtin_bit_cast(float, u);
}
__device__ __forceinline__ bf16x8 ld8b(const float* p) {  // 8 fp32 -> bf16x8
  float4 v0 = *(const float4*)p, v1 = *(const float4*)(p + 4);
  bf16x8 a;
  a[0] = f2b(v0.x); a[1] = f2b(v0.y); a[2] = f2b(v0.z); a[3] = f2b(v0.w);
  a[4] = f2b(v1.x); a[5] = f2b(v1.y); a[6] = f2b(v1.z); a[7] = f2b(v1.w);
  return a;
}

// ---- ws byte layout (<= 3,548,168 B; 3,687,424 proven safe in R6) ----
static constexpr size_t UB_U     = 0;          // u16 [B][FH][H]    1,048,576
static constexpr size_t UB_W     = 1048576;    // f32 [B][FH][H]    2,097,152
static constexpr size_t UB_L     = 3145728;    // f32 [B][FH]           8,192  (contig. after wbuf)
static constexpr size_t UB_STRAT = 3153920;    // f32 [B][F]            1,024
static constexpr size_t UB_MT    = 3154944;    // u16 [3][256][256]   393,216
static constexpr size_t UB_TK    = 3548160;    // u32 [2] ticket counters   8

#define SMEM_BYTES 52224
// k1 : sW2 [256 j][72] = 36,864 | qhh 4,352 @36,864 | qhl 4,352 @41,216 | slog 512 @45,568
// meta: sT [32][264]   = 16,896 @0
// k4 : sdu 33,792 @0 | phu 9,216 @33,792 | plou 9,216 @43,008   (52,224 total)
// k5 : XAh 8,448 @0 | XAl @8,448 | XBh @16,896 | XBl @25,344

// =============== phase: k1 (qh -> u, strategy), b-half bh =======================
__device__ __forceinline__ void dev_k1(char* smem, int f, int hf, int bh,
    const float* __restrict__ query, const float* __restrict__ ipw,
    const float* __restrict__ ipb, const float* __restrict__ stw,
    const float* __restrict__ stb, u16* __restrict__ u, float* __restrict__ strat)
{
  const int tid = threadIdx.x, L = tid & 63, w = tid >> 6;
  const int khi = L >> 4, col = L & 15;
  u16* sW2 = (u16*)smem;                 // [256 j][72]: WkT for 2 heads (64 d + swz pad)
  u16* qhh = (u16*)(smem + 36864);       // qh hi [16 b][136 r-local]
  u16* qhl = (u16*)(smem + 41216);       // qh lo
  float* slog = (float*)(smem + 45568);  // strategy logits [16 b][8 i]

  const int bg = bh * 16 + col;          // this lane's global b

  // query B-frags (bf16-exact), loop-invariant
  bf16x8 qf[8];
  #pragma unroll
  for (int ks = 0; ks < 8; ++ks)
    qf[ks] = ld8b(&query[(size_t)bg * H_ + ks * 32 + khi * 8]);

  // strategy logits via MFMA (f==0,hf==0 blocks, wave 0; each bh does its 16 b)
  if (f == 0 && hf == 0 && w == 0) {
    f32x4 sacc = (f32x4){0.f, 0.f, 0.f, 0.f};
    #pragma unroll
    for (int ks = 0; ks < 8; ++ks) {
      bf16x8 a = (bf16x8){0,0,0,0,0,0,0,0};
      if (col < 8) a = ld8b(&stw[(size_t)col * H_ + ks * 32 + khi * 8]);
      sacc = MFMA(a, qf[ks], sacc);
    }
    if (khi < 2) {   // D row = i = khi*4+r (<8), col -> b_local
      #pragma unroll
      for (int r = 0; r < 4; ++r) {
        int i = khi * 4 + r;
        slog[col * 8 + i] = sacc[r] + stb[i];
      }
    }
  }

  // ---- phase 1: qh GEMM, barrier-free (Wq frags wave-private, direct) ----
  bf16x8 aq[8];
  #pragma unroll
  for (int ks = 0; ks < 8; ++ks)
    aq[ks] = ld8b(&ipw[((size_t)(f * 768) + hf * 128 + w * 16 + col) * H_ + ks * 32 + khi * 8]);
  f32x4 qacc = (f32x4){0.f, 0.f, 0.f, 0.f};
  #pragma unroll
  for (int ks = 0; ks < 8; ++ks)
    qacc = MFMA(aq[ks], qf[ks], qacc);
  // epilogue: + bq, hi/lo split -> qhh/qhl. lane: r = w*16+khi*4+reg, b_local = col
  {
    int r0 = w * 16 + khi * 4;
    float4 bq = *(const float4*)&ipb[f * 768 + hf * 128 + r0];
    float v0 = qacc[0] + bq.x, v1 = qacc[1] + bq.y;
    float v2 = qacc[2] + bq.z, v3 = qacc[3] + bq.w;
    ushort4 hs = make_ushort4(f2b(v0), f2b(v1), f2b(v2), f2b(v3));
    ushort4 ls = make_ushort4(f2b(v0 - b2f(hs.x)), f2b(v1 - b2f(hs.y)),
                              f2b(v2 - b2f(hs.z)), f2b(v3 - b2f(hs.w)));
    *(ushort4*)&qhh[col * 136 + r0] = hs;
    *(ushort4*)&qhl[col * 136 + r0] = ls;
  }
  __syncthreads();

  // strategy softmax (slog written by wave 0, synced above)
  if (f == 0 && hf == 0 && tid < 16) {
    float mx = slog[tid * 8];
    #pragma unroll
    for (int i = 1; i < F_; ++i) mx = fmaxf(mx, slog[tid * 8 + i]);
    float s = 0.f, e[F_];
    #pragma unroll
    for (int i = 0; i < F_; ++i) { e[i] = __expf(slog[tid * 8 + i] - mx); s += e[i]; }
    #pragma unroll
    for (int i = 0; i < F_; ++i) strat[(bh * 16 + tid) * F_ + i] = e[i] / s;
  }

  // ---- phase 2: u, 2 heads per staging round (hp = head-pair) ----
  const float scale = 0.17677669529663687f;
  #pragma unroll
  for (int hp = 0; hp < 2; ++hp) {
    #pragma unroll
    for (int p = 0; p < 8; ++p) {    // stage WkT: 64 d-rows x 256 j, transposed+swizzled
      int gid = tid + 512 * p;
      int dr = gid >> 6, jq = (gid & 63) * 4;   // dr = e*32 + d32 (2 heads)
      float4 v = *(const float4*)&ipw[((size_t)(f * 768 + 256) + hf * 128 + hp * 64 + dr) * H_ + jq];
      float vv[4] = {v.x, v.y, v.z, v.w};
      #pragma unroll
      for (int e2 = 0; e2 < 4; ++e2) {
        int j = jq + e2;
        int m = ((((j >> 4) & 3) ^ ((j >> 2) & 3)) << 3);   // flips slot bits 3-4 only
        sW2[j * 72 + (dr ^ m)] = f2b(vv[e2]);
      }
    }
    __syncthreads();
    #pragma unroll
    for (int e = 0; e < 2; ++e) {    // head h = hf*4 + hp*2 + e
      #pragma unroll
      for (int q = 0; q < 2; ++q) {
        int jt = w * 2 + q;
        bf16x8 a = *(const bf16x8*)&sW2[(jt * 16 + col) * 72 + e * 32
                                        + ((khi ^ (jt & 3) ^ (col >> 2)) << 3)];
        int rl = (hp * 2 + e) * 32 + khi * 8;
        bf16x8 bhf = *(const bf16x8*)&qhh[col * 136 + rl];
        bf16x8 blf = *(const bf16x8*)&qhl[col * 136 + rl];
        f32x4 acc = (f32x4){0.f, 0.f, 0.f, 0.f};
        acc = MFMA(a, bhf, acc);
        acc = MFMA(a, blf, acc);
        int j0 = jt * 16 + khi * 4;
        ushort4 us = make_ushort4(f2b(acc[0] * scale), f2b(acc[1] * scale),
                                  f2b(acc[2] * scale), f2b(acc[3] * scale));
        *(ushort4*)&u[((size_t)(bg * 64) + f * 8 + hf * 4 + hp * 2 + e) * H_ + j0] = us;
      }
    }
    __syncthreads();
  }
}

// =============== phase: metaT transpose =========================================
__device__ __forceinline__ void dev_meta(char* smem, int bid2,
    const float* __restrict__ meta, u16* __restrict__ metaT)
{
  const int tid = threadIdx.x;
  const int s = bid2 >> 3, x0 = (bid2 & 7) * 32;
  u16* sT = (u16*)smem;                        // [32 x][264 r]
  #pragma unroll
  for (int p = 0; p < 4; ++p) {                // load 256 r x 32 x, coalesced
    int idx = tid + 512 * p;
    int r = idx >> 3, xq = (idx & 7) * 4;
    float4 v = *(const float4*)&meta[((size_t)(s * 256) + r) * 256 + x0 + xq];
    sT[(xq + 0) * 264 + r] = f2b(v.x);
    sT[(xq + 1) * 264 + r] = f2b(v.y);
    sT[(xq + 2) * 264 + r] = f2b(v.z);
    sT[(xq + 3) * 264 + r] = f2b(v.w);
  }
  __syncthreads();
  #pragma unroll
  for (int p = 0; p < 2; ++p) {                // store rows of metaT, 16B chunks
    int idx = tid + 512 * p;
    int x = idx >> 5, rq = (idx & 31) * 8;
    bf16x8 v = *(bf16x8*)&sT[x * 264 + rq];
    *(bf16x8*)&metaT[((size_t)(s * 256) + x0 + x) * 256 + rq] = v;
  }
}

// =============== phase: k4 (single docs pass, shift-free exp, W + l) ============
// 256 n per block (4 chunks of 64), grid (8 ns, 32 b) = 256 blocks.
__device__ __forceinline__ void dev_k4(char* smem, int ns, int b,
    const float* __restrict__ docs, const float* __restrict__ cw,
    const u16* __restrict__ u, float* __restrict__ wbuf, float* __restrict__ lbuf)
{
  const int n0 = ns * 256;
  const int tid = threadIdx.x, L = tid & 63, w = tid >> 6;
  const int khi = L >> 4, col = L & 15;
  const int ft = w & 3, nt0 = (w >> 2) * 2;

  u16* sdu  = (u16*)smem;              // docs chunk [64 n][264 j] bf16, col-swizzled
  u16* phu  = (u16*)(smem + 33792);    // (e*cw)_hi [64 fh][72 n]
  u16* plou = (u16*)(smem + 43008);    // (e*cw)_lo

  // loop-invariant u A-fragments for this wave's fh-tile ft
  bf16x8 uf[8];
  #pragma unroll
  for (int ks = 0; ks < 8; ++ks)
    uf[ks] = *(const bf16x8*)&u[((size_t)(b * 64) + ft * 16 + col) * H_ + ks * 32 + khi * 8];

  // prefetch + stage chunk 0 (swizzled store)
  float4 dv[8];
  #pragma unroll
  for (int p = 0; p < 8; ++p) {
    int idx = tid + 512 * p;
    int n = idx >> 6, jq = (idx & 63) * 4;
    dv[p] = *(const float4*)&docs[((size_t)(b * N_) + n0 + n) * H_ + jq];
  }
  #pragma unroll
  for (int p = 0; p < 8; ++p) {
    int idx = tid + 512 * p;
    int n = idx >> 6, jq = (idx & 63) * 4;
    *(ushort4*)&sdu[n * 264 + (jq ^ (((n >> 3) & 3) << 4))] =
        make_ushort4(f2b(dv[p].x), f2b(dv[p].y), f2b(dv[p].z), f2b(dv[p].w));
  }
  __syncthreads();

  f32x4 acc2[4][2];
  #pragma unroll
  for (int mt = 0; mt < 4; ++mt)
    #pragma unroll
    for (int jt = 0; jt < 2; ++jt) acc2[mt][jt] = (f32x4){0.f, 0.f, 0.f, 0.f};
  float eacc[4] = {0.f, 0.f, 0.f, 0.f};

  for (int nc = 0; nc < NCHK_; ++nc) {
    if (nc < NCHK_ - 1) {   // issue next chunk's global loads (hide under MFMA)
      #pragma unroll
      for (int p = 0; p < 8; ++p) {
        int idx = tid + 512 * p;
        int n = idx >> 6, jq = (idx & 63) * 4;
        dv[p] = *(const float4*)&docs[((size_t)(b * N_) + n0 + (nc + 1) * 64 + n) * H_ + jq];
      }
    }
    // scores: D[fh(ft)][n(nt0,nt0+1)] = u . docs^T, K=256
    f32x4 sc0 = (f32x4){0.f, 0.f, 0.f, 0.f}, sc1 = sc0;
    const int nr0 = nt0 * 16 + col, nr1 = (nt0 + 1) * 16 + col;
    const int sw0 = ((nr0 >> 3) & 3) << 4, sw1 = ((nr1 >> 3) & 3) << 4;
    #pragma unroll
    for (int ks = 0; ks < 8; ++ks) {
      bf16x8 b0 = *(const bf16x8*)&sdu[nr0 * 264 + ((ks * 32 + khi * 8) ^ sw0)];
      bf16x8 b1 = *(const bf16x8*)&sdu[nr1 * 264 + ((ks * 32 + khi * 8) ^ sw1)];
      sc0 = MFMA(uf[ks], b0, sc0);
      sc1 = MFMA(uf[ks], b1, sc1);
    }
    // epilogue: e = exp(s*cw); weight = e*cw hi/lo; l-accum
    {
      int ng = n0 + nc * 64 + nt0 * 16 + col;
      float cv0 = cw[(size_t)b * N_ + ng];
      float cv1 = cw[(size_t)b * N_ + ng + 16];
      #pragma unroll
      for (int r = 0; r < 4; ++r) {
        int fh = ft * 16 + khi * 4 + r;
        float ex0 = __expf(sc0[r] * cv0);
        float ex1 = __expf(sc1[r] * cv1);
        eacc[r] += ex0 + ex1;
        float p0 = ex0 * cv0, p1 = ex1 * cv1;
        u16 h0 = f2b(p0), h1 = f2b(p1);
        phu [fh * 72 + nt0 * 16 + col]       = h0;
        plou[fh * 72 + nt0 * 16 + col]       = f2b(p0 - b2f(h0));
        phu [fh * 72 + (nt0 + 1) * 16 + col] = h1;
        plou[fh * 72 + (nt0 + 1) * 16 + col] = f2b(p1 - b2f(h1));
      }
    }
    __syncthreads();   // weights visible; sdu intact

    // W[fh][j] += sum_n weight[fh][n] * docs[n][j]; wave owns j = w*32+jt*16+col
    #pragma unroll
    for (int kk = 0; kk < 2; ++kk) {
      #pragma unroll
      for (int jt = 0; jt < 2; ++jt) {
        int j = w * 32 + jt * 16 + col;
        bf16x8 bb;
        #pragma unroll
        for (int jj = 0; jj < 8; ++jj)
          bb[jj] = (short)sdu[(kk * 32 + khi * 8 + jj) * 264 + (j ^ (khi << 4))];
        #pragma unroll
        for (int mt = 0; mt < 4; ++mt) {
          bf16x8 ah = *(const bf16x8*)&phu [(mt * 16 + col) * 72 + kk * 32 + khi * 8];
          bf16x8 al = *(const bf16x8*)&plou[(mt * 16 + col) * 72 + kk * 32 + khi * 8];
          acc2[mt][jt] = MFMA(ah, bb, acc2[mt][jt]);
          acc2[mt][jt] = MFMA(al, bb, acc2[mt][jt]);
        }
      }
    }
    __syncthreads();   // all reads of sdu/weights done

    if (nc < NCHK_ - 1) {   // stage next chunk from regs
      #pragma unroll
      for (int p = 0; p < 8; ++p) {
        int idx = tid + 512 * p;
        int n = idx >> 6, jq = (idx & 63) * 4;
        *(ushort4*)&sdu[n * 264 + (jq ^ (((n >> 3) & 3) << 4))] =
            make_ushort4(f2b(dv[p].x), f2b(dv[p].y), f2b(dv[p].z), f2b(dv[p].w));
      }
      __syncthreads();
    }
  }
  // merge partial W (one atomic per element; 8 adds per address across ns)
  #pragma unroll
  for (int mt = 0; mt < 4; ++mt)
    #pragma unroll
    for (int jt = 0; jt < 2; ++jt)
      #pragma unroll
      for (int r = 0; r < 4; ++r) {
        int fh = mt * 16 + khi * 4 + r;
        int j = w * 32 + jt * 16 + col;
        atomicAdd(&wbuf[((size_t)(b * 64) + fh) * H_ + j], acc2[mt][jt][r]);
      }
  // l partials: reduce over col (16 lanes), one atomic per (khi,r) lane group
  #pragma unroll
  for (int r = 0; r < 4; ++r) {
    float e = eacc[r];
    e += __shfl_xor(e, 1, 64);
    e += __shfl_xor(e, 2, 64);
    e += __shfl_xor(e, 4, 64);
    e += __shfl_xor(e, 8, 64);
    if (col == 0)
      atomicAdd(&lbuf[(size_t)(b * 64) + ft * 16 + khi * 4 + r], e);
  }
}

// =============== phase: k5 (ctx -> ho0 -> 3 meta steps -> out) ==================
__device__ __forceinline__ void dev_k5(char* smem, int f, int b0,
    const float* __restrict__ ipw, const float* __restrict__ ipb,
    const float* __restrict__ opw, const float* __restrict__ opb,
    const u16* __restrict__ metaT, const float* __restrict__ wbuf,
    const float* __restrict__ lbuf, const float* __restrict__ strat,
    float* __restrict__ out)
{
  const int tid = threadIdx.x, L = tid & 63, w = tid >> 6;   // w = wave 0..7
  const int khi = L >> 4, col = L & 15;

  u16* XAh = (u16*)smem;               // [16 b][264 c] hi/lo
  u16* XAl = (u16*)(smem + 8448);
  u16* XBh = (u16*)(smem + 16896);
  u16* XBl = (u16*)(smem + 25344);

  // ---- ctx: wave w = head h. D[d(2x16 tiles)][b(16)] = Wv_h . (w/l)_h^T ----
  bf16x8 av[2][8];
  #pragma unroll
  for (int mt = 0; mt < 2; ++mt)
    #pragma unroll
    for (int ks = 0; ks < 8; ++ks)
      av[mt][ks] = ld8b(&ipw[((size_t)(f * 768 + 512) + w * 32 + mt * 16 + col) * H_
                             + ks * 32 + khi * 8]);
  const size_t wrow = ((size_t)((b0 + col) * 64) + f * 8 + w) * H_;
  const float li = 1.f / lbuf[(size_t)((b0 + col) * 64) + f * 8 + w];
  f32x4 cacc0 = (f32x4){0.f, 0.f, 0.f, 0.f};
  f32x4 cacc1 = (f32x4){0.f, 0.f, 0.f, 0.f};
  #pragma unroll
  for (int ks = 0; ks < 8; ++ks) {
    const float* p = &wbuf[wrow + ks * 32 + khi * 8];
    float4 v0 = *(const float4*)p, v1 = *(const float4*)(p + 4);
    float vv[8] = {v0.x, v0.y, v0.z, v0.w, v1.x, v1.y, v1.z, v1.w};
    bf16x8 bh, bl;
    #pragma unroll
    for (int e = 0; e < 8; ++e) {
      float x = vv[e] * li;
      u16 h = f2b(x);
      bh[e] = (short)h;
      bl[e] = (short)f2b(x - b2f(h));
    }
    cacc0 = MFMA(av[0][ks], bh, cacc0); cacc0 = MFMA(av[0][ks], bl, cacc0);
    cacc1 = MFMA(av[1][ks], bh, cacc1); cacc1 = MFMA(av[1][ks], bl, cacc1);
  }
  // ctx + bv -> XA hi/lo. lane owns (d = mt*16+khi*4+r, b = col) for h = w.
  #pragma unroll
  for (int mt = 0; mt < 2; ++mt) {
    f32x4 cv = mt ? cacc1 : cacc0;
    #pragma unroll
    for (int r = 0; r < 4; ++r) {
      int d = mt * 16 + khi * 4 + r;
      float vv = cv[r] + ipb[f * 768 + 512 + w * 32 + d];
      u16 hi = f2b(vv);
      XAh[col * 264 + w * 32 + d] = hi;
      XAl[col * 264 + w * 32 + d] = f2b(vv - b2f(hi));
    }
  }

  // prefetch Wo B-frags (wave-private rows (w*2+q)*16+col) before the barrier
  bf16x8 bw[2][8];
  #pragma unroll
  for (int q = 0; q < 2; ++q)
    #pragma unroll
    for (int ks = 0; ks < 8; ++ks)
      bw[q][ks] = ld8b(&opw[((size_t)(f * 256) + (w * 2 + q) * 16 + col) * H_
                            + ks * 32 + khi * 8]);
  __syncthreads();   // XA complete

  // ---- ho0: D[b][x] = ctx . Wo^T + bo ; waves own x-tiles (w*2+q)*16 ----
  f32x4 hr0, hr1;
  {
    float bo0 = opb[f * 256 + (w * 2 + 0) * 16 + col];
    float bo1 = opb[f * 256 + (w * 2 + 1) * 16 + col];
    hr0 = (f32x4){bo0, bo0, bo0, bo0};
    hr1 = (f32x4){bo1, bo1, bo1, bo1};
  }
  #pragma unroll
  for (int ks = 0; ks < 8; ++ks) {
    bf16x8 ah = *(const bf16x8*)&XAh[col * 264 + ks * 32 + khi * 8];
    bf16x8 al = *(const bf16x8*)&XAl[col * 264 + ks * 32 + khi * 8];
    hr0 = MFMA(ah, bw[0][ks], hr0); hr0 = MFMA(al, bw[0][ks], hr0);
    hr1 = MFMA(ah, bw[1][ks], hr1); hr1 = MFMA(al, bw[1][ks], hr1);
  }

  auto spill = [&](u16* Oh, u16* Ol) {
    #pragma unroll
    for (int q = 0; q < 2; ++q) {
      f32x4 hv = q ? hr1 : hr0;
      int x = (w * 2 + q) * 16 + col;
      #pragma unroll
      for (int r = 0; r < 4; ++r) {
        u16 hi = f2b(hv[r]);
        Oh[(khi * 4 + r) * 264 + x] = hi;
        Ol[(khi * 4 + r) * 264 + x] = f2b(hv[r] - b2f(hi));
      }
    }
  };
  auto meta_mm = [&](const u16* Ah_, const u16* Al_, int s) {
    f32x4 n0 = hr0, n1 = hr1;
    #pragma unroll
    for (int ks = 0; ks < 8; ++ks) {
      bf16x8 ah = *(const bf16x8*)&Ah_[col * 264 + ks * 32 + khi * 8];
      bf16x8 al = *(const bf16x8*)&Al_[col * 264 + ks * 32 + khi * 8];
      const u16* mrow = &metaT[((size_t)(s * 256) + (w * 2) * 16 + col) * 256 + ks * 32 + khi * 8];
      bf16x8 m0 = *(const bf16x8*)mrow;
      bf16x8 m1 = *(const bf16x8*)(mrow + 16 * 256);
      n0 = MFMA(ah, m0, n0); n0 = MFMA(al, m0, n0);
      n1 = MFMA(ah, m1, n1); n1 = MFMA(al, m1, n1);
    }
    hr0 = n0; hr1 = n1;
  };

  spill(XBh, XBl);            // ho0
  __syncthreads();
  meta_mm(XBh, XBl, 0);
  spill(XAh, XAl);
  __syncthreads();
  meta_mm(XAh, XAl, 1);
  spill(XBh, XBl);
  __syncthreads();
  meta_mm(XBh, XBl, 2);

  // fused k6: out[b][x] += strat[b][f] * ho  (out pre-zeroed; 8 adds/address)
  #pragma unroll
  for (int q = 0; q < 2; ++q) {
    f32x4 hv = q ? hr1 : hr0;
    int x = (w * 2 + q) * 16 + col;
    #pragma unroll
    for (int r = 0; r < 4; ++r) {
      int b = khi * 4 + r;
      float sv = strat[(b0 + b) * F_ + f];
      atomicAdd(&out[(size_t)(b0 + b) * H_ + x], sv * hv[r]);
    }
  }
}

// =============== kernels =======================================================
// k1_all: grid 72. 0-31: k1 (f,hf,bh). 32-55: metaT. 56-71: zero wbuf/lbuf/out/tk.
__global__ __launch_bounds__(512) void k1_all(
    const float* __restrict__ query, const float* __restrict__ ipw,
    const float* __restrict__ ipb, const float* __restrict__ stw,
    const float* __restrict__ stb, const float* __restrict__ meta,
    u16* __restrict__ u, u16* __restrict__ metaT, float* __restrict__ strat,
    float* __restrict__ wbuf, float* __restrict__ out, unsigned* __restrict__ tk)
{
  __shared__ __align__(16) char smem[SMEM_BYTES];
  const int bid = blockIdx.x, tid = threadIdx.x;
  if (bid < 32) {
    dev_k1(smem, bid >> 2, (bid >> 1) & 1, bid & 1, query, ipw, ipb, stw, stb, u, strat);
  } else if (bid < 56) {
    dev_meta(smem, bid - 32, meta, metaT);
  } else {
    int zb = bid - 56;   // 16 blocks zero wbuf+lbuf (131,584 f32x4 contiguous)
    float4 z4 = make_float4(0.f, 0.f, 0.f, 0.f);
    float4* z = (float4*)wbuf;
    for (int i = zb * 512 + tid; i < 131584; i += 16 * 512) z[i] = z4;
    if (zb < 4) ((float4*)out)[zb * 512 + tid] = z4;   // out: 2,048 f32x4
    if (zb == 0 && tid < 2) tk[tid] = 0u;              // ticket counters
  }
}

// k4k5_fused: grid (8 ns, 32 b). Every block runs dev_k4; the last 8 finishers
// of each 128-block b-tile (split-K last-block ticket) each run one dev_k5(f).
__global__ __launch_bounds__(512) void k4k5_fused(
    const float* __restrict__ docs, const float* __restrict__ cw,
    const u16* __restrict__ u, float* __restrict__ wbuf, float* __restrict__ lbuf,
    const float* __restrict__ ipw, const float* __restrict__ ipb,
    const float* __restrict__ opw, const float* __restrict__ opb,
    const u16* __restrict__ metaT, const float* __restrict__ strat,
    float* __restrict__ out, unsigned* __restrict__ tk)
{
  __shared__ __align__(16) char smem[SMEM_BYTES];
  __shared__ unsigned tkt;
  const int ns = blockIdx.x, b = blockIdx.y;

  dev_k4(smem, ns, b, docs, cw, u, wbuf, lbuf);

  // ---- split-K last-block handoff ----
  __threadfence();          // drain this thread's W/l atomics to device scope
  __syncthreads();          // all threads of block done
  if (threadIdx.x == 0)
    tkt = __hip_atomic_fetch_add(&tk[b >> 4], 1u, __ATOMIC_ACQ_REL,
                                 __HIP_MEMORY_SCOPE_AGENT);
  __syncthreads();
  unsigned t = tkt;
  if (t >= 120u) {          // one of the last 8 of this b-tile's 128 blocks
    __threadfence();        // acquire: invalidate local caches before W reads
    dev_k5(smem, (int)(t - 120u), (b >> 4) * 16,
           ipw, ipb, opw, opb, metaT, wbuf, lbuf, strat, out);
  }
}

extern "C" void kernel_launch(void* const* d_in, const int* in_sizes, int n_in,
                              void* d_out, int out_size, void* d_ws, size_t ws_size,
                              hipStream_t stream) {
  const float* query = (const float*)d_in[0];
  const float* docs  = (const float*)d_in[1];
  const float* cw    = (const float*)d_in[2];
  // d_in[3] context_history: unused by the reference
  const float* ipw   = (const float*)d_in[4];
  const float* ipb   = (const float*)d_in[5];
  const float* opw   = (const float*)d_in[6];
  const float* opb   = (const float*)d_in[7];
  const float* stw   = (const float*)d_in[8];
  const float* stb   = (const float*)d_in[9];
  const float* meta  = (const float*)d_in[10];
  float* out = (float*)d_out;

  char* base = (char*)d_ws;
  u16*      u     = (u16*)(base + UB_U);
  float*    wbuf  = (float*)(base + UB_W);
  float*    lbuf  = (float*)(base + UB_L);
  float*    strat = (float*)(base + UB_STRAT);
  u16*      metaT = (u16*)(base + UB_MT);
  unsigned* tk    = (unsigned*)(base + UB_TK);

  k1_all<<<dim3(72), 512, 0, stream>>>(query, ipw, ipb, stw, stb, meta,
                                       u, metaT, strat, wbuf, out, tk);
  k4k5_fused<<<dim3(NCH_, B_), 512, 0, stream>>>(docs, cw, u, wbuf, lbuf,
                                                 ipw, ipb, opw, opb, metaT,
                                                 strat, out, tk);
}

// Round 10
// 179.980 us; speedup vs baseline: 1.2504x; 1.2504x over previous
//
#include <hip/hip_runtime.h>
#include <hip/hip_bf16.h>

// MetaAdaptiveFusion: B=32, N=2048, H=256, F=8, NH=8, dh=32, 3 meta steps.
// Inputs: fp32 buffers holding bf16-quantized values -> bf16 casts of INPUTS are
// LOSSLESS. Computed activations (qh, w, ctx, ho, e*cw) are hi/lo-split
// compensated bf16; residual carries stay fp32. Output fp32.
//
// R17: best-of reassembly after two failed fusion experiments (R14 coop
// grid-sync: +115us; R16 last-block ticket: k5 tail ran at 16-block parallelism
// against a docs-flushed L2 -> HBM-latency-bound, +30us). Structure:
//   k1_all  (R15): 72 blocks = 32 k1 (barrier-free qh, 2-head u rounds)
//                  + 24 metaT + 16 zeroing (absorbs both memsets).
//   k4_sep  (R12/R13 geometry, fastest measured ~41us): grid (8,32)=256 blocks,
//                  256 n/block, 4 chunks, 4.2M merge atomics.
//   k5_sep  (R13): 16 blocks, wave-private weights direct global->reg.
// Math bit-identical to R13 -> absmax unchanged.
// Fragment layouts per verified gfx950 conventions (A: m=lane&15,
// k=(lane>>4)*8+j ; B: n=lane&15 same k ; D: col=lane&15, row=(lane>>4)*4+reg).

#define B_ 32
#define N_ 2048
#define H_ 256
#define F_ 8
#define FH_ 64
#define NCH_ 8    // 8 n-split blocks of 256 docs
#define NCHK_ 4   // chunks of 64 n per block

typedef unsigned short u16;
typedef __attribute__((ext_vector_type(8))) short bf16x8;   // 8 bf16 (4 VGPRs)
typedef __attribute__((ext_vector_type(4))) float f32x4;
#define MFMA(a, b, c) __builtin_amdgcn_mfma_f32_16x16x32_bf16((a), (b), (c), 0, 0, 0)

__device__ __forceinline__ u16 f2b(float x) {   // fp32 -> bf16 bits, RNE
  unsigned u = __builtin_bit_cast(unsigned, x);
  return (u16)((u + 0x7fffu + ((u >> 16) & 1u)) >> 16);
}
__device__ __forceinline__ float b2f(u16 h) {
  unsigned u = ((unsigned)h) << 16;
  return __builtin_bit_cast(float, u);
}
__device__ __forceinline__ bf16x8 ld8b(const float* p) {  // 8 fp32 -> bf16x8
  float4 v0 = *(const float4*)p, v1 = *(const float4*)(p + 4);
  bf16x8 a;
  a[0] = f2b(v0.x); a[1] = f2b(v0.y); a[2] = f2b(v0.z); a[3] = f2b(v0.w);
  a[4] = f2b(v1.x); a[5] = f2b(v1.y); a[6] = f2b(v1.z); a[7] = f2b(v1.w);
  return a;
}

// ---- ws byte layout (<= 3,548,160 B; 3,687,424 proven safe in R6) ----
static constexpr size_t UB_U     = 0;          // u16 [B][FH][H]    1,048,576
static constexpr size_t UB_W     = 1048576;    // f32 [B][FH][H]    2,097,152
static constexpr size_t UB_L     = 3145728;    // f32 [B][FH]           8,192  (contig. after wbuf)
static constexpr size_t UB_STRAT = 3153920;    // f32 [B][F]            1,024
static constexpr size_t UB_MT    = 3154944;    // u16 [3][256][256]   393,216

#define SMEM_BYTES 52224
// k1 : sW2 [256 j][72] = 36,864 | qhh 4,352 @36,864 | qhl 4,352 @41,216 | slog 512 @45,568
// meta: sT [32][264]   = 16,896 @0
// k4 : sdu 33,792 @0 | phu 9,216 @33,792 | plou 9,216 @43,008   (52,224 total)
// k5 : XAh 8,448 @0 | XAl @8,448 | XBh @16,896 | XBl @25,344

// =============== phase: k1 (qh -> u, strategy), b-half bh =======================
__device__ __forceinline__ void dev_k1(char* smem, int f, int hf, int bh,
    const float* __restrict__ query, const float* __restrict__ ipw,
    const float* __restrict__ ipb, const float* __restrict__ stw,
    const float* __restrict__ stb, u16* __restrict__ u, float* __restrict__ strat)
{
  const int tid = threadIdx.x, L = tid & 63, w = tid >> 6;
  const int khi = L >> 4, col = L & 15;
  u16* sW2 = (u16*)smem;                 // [256 j][72]: WkT for 2 heads (64 d + swz pad)
  u16* qhh = (u16*)(smem + 36864);       // qh hi [16 b][136 r-local]
  u16* qhl = (u16*)(smem + 41216);       // qh lo
  float* slog = (float*)(smem + 45568);  // strategy logits [16 b][8 i]

  const int bg = bh * 16 + col;          // this lane's global b

  // query B-frags (bf16-exact), loop-invariant
  bf16x8 qf[8];
  #pragma unroll
  for (int ks = 0; ks < 8; ++ks)
    qf[ks] = ld8b(&query[(size_t)bg * H_ + ks * 32 + khi * 8]);

  // strategy logits via MFMA (f==0,hf==0 blocks, wave 0; each bh does its 16 b)
  if (f == 0 && hf == 0 && w == 0) {
    f32x4 sacc = (f32x4){0.f, 0.f, 0.f, 0.f};
    #pragma unroll
    for (int ks = 0; ks < 8; ++ks) {
      bf16x8 a = (bf16x8){0,0,0,0,0,0,0,0};
      if (col < 8) a = ld8b(&stw[(size_t)col * H_ + ks * 32 + khi * 8]);
      sacc = MFMA(a, qf[ks], sacc);
    }
    if (khi < 2) {   // D row = i = khi*4+r (<8), col -> b_local
      #pragma unroll
      for (int r = 0; r < 4; ++r) {
        int i = khi * 4 + r;
        slog[col * 8 + i] = sacc[r] + stb[i];
      }
    }
  }

  // ---- phase 1: qh GEMM, barrier-free (Wq frags wave-private, direct) ----
  bf16x8 aq[8];
  #pragma unroll
  for (int ks = 0; ks < 8; ++ks)
    aq[ks] = ld8b(&ipw[((size_t)(f * 768) + hf * 128 + w * 16 + col) * H_ + ks * 32 + khi * 8]);
  f32x4 qacc = (f32x4){0.f, 0.f, 0.f, 0.f};
  #pragma unroll
  for (int ks = 0; ks < 8; ++ks)
    qacc = MFMA(aq[ks], qf[ks], qacc);
  // epilogue: + bq, hi/lo split -> qhh/qhl. lane: r = w*16+khi*4+reg, b_local = col
  {
    int r0 = w * 16 + khi * 4;
    float4 bq = *(const float4*)&ipb[f * 768 + hf * 128 + r0];
    float v0 = qacc[0] + bq.x, v1 = qacc[1] + bq.y;
    float v2 = qacc[2] + bq.z, v3 = qacc[3] + bq.w;
    ushort4 hs = make_ushort4(f2b(v0), f2b(v1), f2b(v2), f2b(v3));
    ushort4 ls = make_ushort4(f2b(v0 - b2f(hs.x)), f2b(v1 - b2f(hs.y)),
                              f2b(v2 - b2f(hs.z)), f2b(v3 - b2f(hs.w)));
    *(ushort4*)&qhh[col * 136 + r0] = hs;
    *(ushort4*)&qhl[col * 136 + r0] = ls;
  }
  __syncthreads();

  // strategy softmax (slog written by wave 0, synced above)
  if (f == 0 && hf == 0 && tid < 16) {
    float mx = slog[tid * 8];
    #pragma unroll
    for (int i = 1; i < F_; ++i) mx = fmaxf(mx, slog[tid * 8 + i]);
    float s = 0.f, e[F_];
    #pragma unroll
    for (int i = 0; i < F_; ++i) { e[i] = __expf(slog[tid * 8 + i] - mx); s += e[i]; }
    #pragma unroll
    for (int i = 0; i < F_; ++i) strat[(bh * 16 + tid) * F_ + i] = e[i] / s;
  }

  // ---- phase 2: u, 2 heads per staging round (hp = head-pair) ----
  const float scale = 0.17677669529663687f;
  #pragma unroll
  for (int hp = 0; hp < 2; ++hp) {
    #pragma unroll
    for (int p = 0; p < 8; ++p) {    // stage WkT: 64 d-rows x 256 j, transposed+swizzled
      int gid = tid + 512 * p;
      int dr = gid >> 6, jq = (gid & 63) * 4;   // dr = e*32 + d32 (2 heads)
      float4 v = *(const float4*)&ipw[((size_t)(f * 768 + 256) + hf * 128 + hp * 64 + dr) * H_ + jq];
      float vv[4] = {v.x, v.y, v.z, v.w};
      #pragma unroll
      for (int e2 = 0; e2 < 4; ++e2) {
        int j = jq + e2;
        int m = ((((j >> 4) & 3) ^ ((j >> 2) & 3)) << 3);   // flips slot bits 3-4 only
        sW2[j * 72 + (dr ^ m)] = f2b(vv[e2]);
      }
    }
    __syncthreads();
    #pragma unroll
    for (int e = 0; e < 2; ++e) {    // head h = hf*4 + hp*2 + e
      #pragma unroll
      for (int q = 0; q < 2; ++q) {
        int jt = w * 2 + q;
        bf16x8 a = *(const bf16x8*)&sW2[(jt * 16 + col) * 72 + e * 32
                                        + ((khi ^ (jt & 3) ^ (col >> 2)) << 3)];
        int rl = (hp * 2 + e) * 32 + khi * 8;
        bf16x8 bhf = *(const bf16x8*)&qhh[col * 136 + rl];
        bf16x8 blf = *(const bf16x8*)&qhl[col * 136 + rl];
        f32x4 acc = (f32x4){0.f, 0.f, 0.f, 0.f};
        acc = MFMA(a, bhf, acc);
        acc = MFMA(a, blf, acc);
        int j0 = jt * 16 + khi * 4;
        ushort4 us = make_ushort4(f2b(acc[0] * scale), f2b(acc[1] * scale),
                                  f2b(acc[2] * scale), f2b(acc[3] * scale));
        *(ushort4*)&u[((size_t)(bg * 64) + f * 8 + hf * 4 + hp * 2 + e) * H_ + j0] = us;
      }
    }
    __syncthreads();
  }
}

// =============== phase: metaT transpose =========================================
__device__ __forceinline__ void dev_meta(char* smem, int bid2,
    const float* __restrict__ meta, u16* __restrict__ metaT)
{
  const int tid = threadIdx.x;
  const int s = bid2 >> 3, x0 = (bid2 & 7) * 32;
  u16* sT = (u16*)smem;                        // [32 x][264 r]
  #pragma unroll
  for (int p = 0; p < 4; ++p) {                // load 256 r x 32 x, coalesced
    int idx = tid + 512 * p;
    int r = idx >> 3, xq = (idx & 7) * 4;
    float4 v = *(const float4*)&meta[((size_t)(s * 256) + r) * 256 + x0 + xq];
    sT[(xq + 0) * 264 + r] = f2b(v.x);
    sT[(xq + 1) * 264 + r] = f2b(v.y);
    sT[(xq + 2) * 264 + r] = f2b(v.z);
    sT[(xq + 3) * 264 + r] = f2b(v.w);
  }
  __syncthreads();
  #pragma unroll
  for (int p = 0; p < 2; ++p) {                // store rows of metaT, 16B chunks
    int idx = tid + 512 * p;
    int x = idx >> 5, rq = (idx & 31) * 8;
    bf16x8 v = *(bf16x8*)&sT[x * 264 + rq];
    *(bf16x8*)&metaT[((size_t)(s * 256) + x0 + x) * 256 + rq] = v;
  }
}

// =============== phase: k4 (single docs pass, shift-free exp, W + l) ============
// 256 n per block (4 chunks of 64), grid (8 ns, 32 b) = 256 blocks.
__device__ __forceinline__ void dev_k4(char* smem, int ns, int b,
    const float* __restrict__ docs, const float* __restrict__ cw,
    const u16* __restrict__ u, float* __restrict__ wbuf, float* __restrict__ lbuf)
{
  const int n0 = ns * 256;
  const int tid = threadIdx.x, L = tid & 63, w = tid >> 6;
  const int khi = L >> 4, col = L & 15;
  const int ft = w & 3, nt0 = (w >> 2) * 2;

  u16* sdu  = (u16*)smem;              // docs chunk [64 n][264 j] bf16, col-swizzled
  u16* phu  = (u16*)(smem + 33792);    // (e*cw)_hi [64 fh][72 n]
  u16* plou = (u16*)(smem + 43008);    // (e*cw)_lo

  // loop-invariant u A-fragments for this wave's fh-tile ft
  bf16x8 uf[8];
  #pragma unroll
  for (int ks = 0; ks < 8; ++ks)
    uf[ks] = *(const bf16x8*)&u[((size_t)(b * 64) + ft * 16 + col) * H_ + ks * 32 + khi * 8];

  // prefetch + stage chunk 0 (swizzled store)
  float4 dv[8];
  #pragma unroll
  for (int p = 0; p < 8; ++p) {
    int idx = tid + 512 * p;
    int n = idx >> 6, jq = (idx & 63) * 4;
    dv[p] = *(const float4*)&docs[((size_t)(b * N_) + n0 + n) * H_ + jq];
  }
  #pragma unroll
  for (int p = 0; p < 8; ++p) {
    int idx = tid + 512 * p;
    int n = idx >> 6, jq = (idx & 63) * 4;
    *(ushort4*)&sdu[n * 264 + (jq ^ (((n >> 3) & 3) << 4))] =
        make_ushort4(f2b(dv[p].x), f2b(dv[p].y), f2b(dv[p].z), f2b(dv[p].w));
  }
  __syncthreads();

  f32x4 acc2[4][2];
  #pragma unroll
  for (int mt = 0; mt < 4; ++mt)
    #pragma unroll
    for (int jt = 0; jt < 2; ++jt) acc2[mt][jt] = (f32x4){0.f, 0.f, 0.f, 0.f};
  float eacc[4] = {0.f, 0.f, 0.f, 0.f};

  for (int nc = 0; nc < NCHK_; ++nc) {
    if (nc < NCHK_ - 1) {   // issue next chunk's global loads (hide under MFMA)
      #pragma unroll
      for (int p = 0; p < 8; ++p) {
        int idx = tid + 512 * p;
        int n = idx >> 6, jq = (idx & 63) * 4;
        dv[p] = *(const float4*)&docs[((size_t)(b * N_) + n0 + (nc + 1) * 64 + n) * H_ + jq];
      }
    }
    // scores: D[fh(ft)][n(nt0,nt0+1)] = u . docs^T, K=256
    f32x4 sc0 = (f32x4){0.f, 0.f, 0.f, 0.f}, sc1 = sc0;
    const int nr0 = nt0 * 16 + col, nr1 = (nt0 + 1) * 16 + col;
    const int sw0 = ((nr0 >> 3) & 3) << 4, sw1 = ((nr1 >> 3) & 3) << 4;
    #pragma unroll
    for (int ks = 0; ks < 8; ++ks) {
      bf16x8 b0 = *(const bf16x8*)&sdu[nr0 * 264 + ((ks * 32 + khi * 8) ^ sw0)];
      bf16x8 b1 = *(const bf16x8*)&sdu[nr1 * 264 + ((ks * 32 + khi * 8) ^ sw1)];
      sc0 = MFMA(uf[ks], b0, sc0);
      sc1 = MFMA(uf[ks], b1, sc1);
    }
    // epilogue: e = exp(s*cw); weight = e*cw hi/lo; l-accum
    {
      int ng = n0 + nc * 64 + nt0 * 16 + col;
      float cv0 = cw[(size_t)b * N_ + ng];
      float cv1 = cw[(size_t)b * N_ + ng + 16];
      #pragma unroll
      for (int r = 0; r < 4; ++r) {
        int fh = ft * 16 + khi * 4 + r;
        float ex0 = __expf(sc0[r] * cv0);
        float ex1 = __expf(sc1[r] * cv1);
        eacc[r] += ex0 + ex1;
        float p0 = ex0 * cv0, p1 = ex1 * cv1;
        u16 h0 = f2b(p0), h1 = f2b(p1);
        phu [fh * 72 + nt0 * 16 + col]       = h0;
        plou[fh * 72 + nt0 * 16 + col]       = f2b(p0 - b2f(h0));
        phu [fh * 72 + (nt0 + 1) * 16 + col] = h1;
        plou[fh * 72 + (nt0 + 1) * 16 + col] = f2b(p1 - b2f(h1));
      }
    }
    __syncthreads();   // weights visible; sdu intact

    // W[fh][j] += sum_n weight[fh][n] * docs[n][j]; wave owns j = w*32+jt*16+col
    #pragma unroll
    for (int kk = 0; kk < 2; ++kk) {
      #pragma unroll
      for (int jt = 0; jt < 2; ++jt) {
        int j = w * 32 + jt * 16 + col;
        bf16x8 bb;
        #pragma unroll
        for (int jj = 0; jj < 8; ++jj)
          bb[jj] = (short)sdu[(kk * 32 + khi * 8 + jj) * 264 + (j ^ (khi << 4))];
        #pragma unroll
        for (int mt = 0; mt < 4; ++mt) {
          bf16x8 ah = *(const bf16x8*)&phu [(mt * 16 + col) * 72 + kk * 32 + khi * 8];
          bf16x8 al = *(const bf16x8*)&plou[(mt * 16 + col) * 72 + kk * 32 + khi * 8];
          acc2[mt][jt] = MFMA(ah, bb, acc2[mt][jt]);
          acc2[mt][jt] = MFMA(al, bb, acc2[mt][jt]);
        }
      }
    }
    __syncthreads();   // all reads of sdu/weights done

    if (nc < NCHK_ - 1) {   // stage next chunk from regs
      #pragma unroll
      for (int p = 0; p < 8; ++p) {
        int idx = tid + 512 * p;
        int n = idx >> 6, jq = (idx & 63) * 4;
        *(ushort4*)&sdu[n * 264 + (jq ^ (((n >> 3) & 3) << 4))] =
            make_ushort4(f2b(dv[p].x), f2b(dv[p].y), f2b(dv[p].z), f2b(dv[p].w));
      }
      __syncthreads();
    }
  }
  // merge partial W (one atomic per element; 8 adds per address across ns)
  #pragma unroll
  for (int mt = 0; mt < 4; ++mt)
    #pragma unroll
    for (int jt = 0; jt < 2; ++jt)
      #pragma unroll
      for (int r = 0; r < 4; ++r) {
        int fh = mt * 16 + khi * 4 + r;
        int j = w * 32 + jt * 16 + col;
        atomicAdd(&wbuf[((size_t)(b * 64) + fh) * H_ + j], acc2[mt][jt][r]);
      }
  // l partials: reduce over col (16 lanes), one atomic per (khi,r) lane group
  #pragma unroll
  for (int r = 0; r < 4; ++r) {
    float e = eacc[r];
    e += __shfl_xor(e, 1, 64);
    e += __shfl_xor(e, 2, 64);
    e += __shfl_xor(e, 4, 64);
    e += __shfl_xor(e, 8, 64);
    if (col == 0)
      atomicAdd(&lbuf[(size_t)(b * 64) + ft * 16 + khi * 4 + r], e);
  }
}

// =============== phase: k5 (ctx -> ho0 -> 3 meta steps -> out) ==================
__device__ __forceinline__ void dev_k5(char* smem, int f, int b0,
    const float* __restrict__ ipw, const float* __restrict__ ipb,
    const float* __restrict__ opw, const float* __restrict__ opb,
    const u16* __restrict__ metaT, const float* __restrict__ wbuf,
    const float* __restrict__ lbuf, const float* __restrict__ strat,
    float* __restrict__ out)
{
  const int tid = threadIdx.x, L = tid & 63, w = tid >> 6;   // w = wave 0..7
  const int khi = L >> 4, col = L & 15;

  u16* XAh = (u16*)smem;               // [16 b][264 c] hi/lo
  u16* XAl = (u16*)(smem + 8448);
  u16* XBh = (u16*)(smem + 16896);
  u16* XBl = (u16*)(smem + 25344);

  // ---- ctx: wave w = head h. D[d(2x16 tiles)][b(16)] = Wv_h . (w/l)_h^T ----
  bf16x8 av[2][8];
  #pragma unroll
  for (int mt = 0; mt < 2; ++mt)
    #pragma unroll
    for (int ks = 0; ks < 8; ++ks)
      av[mt][ks] = ld8b(&ipw[((size_t)(f * 768 + 512) + w * 32 + mt * 16 + col) * H_
                             + ks * 32 + khi * 8]);
  const size_t wrow = ((size_t)((b0 + col) * 64) + f * 8 + w) * H_;
  const float li = 1.f / lbuf[(size_t)((b0 + col) * 64) + f * 8 + w];
  f32x4 cacc0 = (f32x4){0.f, 0.f, 0.f, 0.f};
  f32x4 cacc1 = (f32x4){0.f, 0.f, 0.f, 0.f};
  #pragma unroll
  for (int ks = 0; ks < 8; ++ks) {
    const float* p = &wbuf[wrow + ks * 32 + khi * 8];
    float4 v0 = *(const float4*)p, v1 = *(const float4*)(p + 4);
    float vv[8] = {v0.x, v0.y, v0.z, v0.w, v1.x, v1.y, v1.z, v1.w};
    bf16x8 bh, bl;
    #pragma unroll
    for (int e = 0; e < 8; ++e) {
      float x = vv[e] * li;
      u16 h = f2b(x);
      bh[e] = (short)h;
      bl[e] = (short)f2b(x - b2f(h));
    }
    cacc0 = MFMA(av[0][ks], bh, cacc0); cacc0 = MFMA(av[0][ks], bl, cacc0);
    cacc1 = MFMA(av[1][ks], bh, cacc1); cacc1 = MFMA(av[1][ks], bl, cacc1);
  }
  // ctx + bv -> XA hi/lo. lane owns (d = mt*16+khi*4+r, b = col) for h = w.
  #pragma unroll
  for (int mt = 0; mt < 2; ++mt) {
    f32x4 cv = mt ? cacc1 : cacc0;
    #pragma unroll
    for (int r = 0; r < 4; ++r) {
      int d = mt * 16 + khi * 4 + r;
      float vv = cv[r] + ipb[f * 768 + 512 + w * 32 + d];
      u16 hi = f2b(vv);
      XAh[col * 264 + w * 32 + d] = hi;
      XAl[col * 264 + w * 32 + d] = f2b(vv - b2f(hi));
    }
  }

  // prefetch Wo B-frags (wave-private rows (w*2+q)*16+col) before the barrier
  bf16x8 bw[2][8];
  #pragma unroll
  for (int q = 0; q < 2; ++q)
    #pragma unroll
    for (int ks = 0; ks < 8; ++ks)
      bw[q][ks] = ld8b(&opw[((size_t)(f * 256) + (w * 2 + q) * 16 + col) * H_
                            + ks * 32 + khi * 8]);
  __syncthreads();   // XA complete

  // ---- ho0: D[b][x] = ctx . Wo^T + bo ; waves own x-tiles (w*2+q)*16 ----
  f32x4 hr0, hr1;
  {
    float bo0 = opb[f * 256 + (w * 2 + 0) * 16 + col];
    float bo1 = opb[f * 256 + (w * 2 + 1) * 16 + col];
    hr0 = (f32x4){bo0, bo0, bo0, bo0};
    hr1 = (f32x4){bo1, bo1, bo1, bo1};
  }
  #pragma unroll
  for (int ks = 0; ks < 8; ++ks) {
    bf16x8 ah = *(const bf16x8*)&XAh[col * 264 + ks * 32 + khi * 8];
    bf16x8 al = *(const bf16x8*)&XAl[col * 264 + ks * 32 + khi * 8];
    hr0 = MFMA(ah, bw[0][ks], hr0); hr0 = MFMA(al, bw[0][ks], hr0);
    hr1 = MFMA(ah, bw[1][ks], hr1); hr1 = MFMA(al, bw[1][ks], hr1);
  }

  auto spill = [&](u16* Oh, u16* Ol) {
    #pragma unroll
    for (int q = 0; q < 2; ++q) {
      f32x4 hv = q ? hr1 : hr0;
      int x = (w * 2 + q) * 16 + col;
      #pragma unroll
      for (int r = 0; r < 4; ++r) {
        u16 hi = f2b(hv[r]);
        Oh[(khi * 4 + r) * 264 + x] = hi;
        Ol[(khi * 4 + r) * 264 + x] = f2b(hv[r] - b2f(hi));
      }
    }
  };
  auto meta_mm = [&](const u16* Ah_, const u16* Al_, int s) {
    f32x4 n0 = hr0, n1 = hr1;
    #pragma unroll
    for (int ks = 0; ks < 8; ++ks) {
      bf16x8 ah = *(const bf16x8*)&Ah_[col * 264 + ks * 32 + khi * 8];
      bf16x8 al = *(const bf16x8*)&Al_[col * 264 + ks * 32 + khi * 8];
      const u16* mrow = &metaT[((size_t)(s * 256) + (w * 2) * 16 + col) * 256 + ks * 32 + khi * 8];
      bf16x8 m0 = *(const bf16x8*)mrow;
      bf16x8 m1 = *(const bf16x8*)(mrow + 16 * 256);
      n0 = MFMA(ah, m0, n0); n0 = MFMA(al, m0, n0);
      n1 = MFMA(ah, m1, n1); n1 = MFMA(al, m1, n1);
    }
    hr0 = n0; hr1 = n1;
  };

  spill(XBh, XBl);            // ho0
  __syncthreads();
  meta_mm(XBh, XBl, 0);
  spill(XAh, XAl);
  __syncthreads();
  meta_mm(XAh, XAl, 1);
  spill(XBh, XBl);
  __syncthreads();
  meta_mm(XBh, XBl, 2);

  // fused k6: out[b][x] += strat[b][f] * ho  (out pre-zeroed; 8 adds/address)
  #pragma unroll
  for (int q = 0; q < 2; ++q) {
    f32x4 hv = q ? hr1 : hr0;
    int x = (w * 2 + q) * 16 + col;
    #pragma unroll
    for (int r = 0; r < 4; ++r) {
      int b = khi * 4 + r;
      float sv = strat[(b0 + b) * F_ + f];
      atomicAdd(&out[(size_t)(b0 + b) * H_ + x], sv * hv[r]);
    }
  }
}

// =============== kernels =======================================================
// k1_all: grid 72. 0-31: k1 (f,hf,bh). 32-55: metaT. 56-71: zero wbuf/lbuf/out.
__global__ __launch_bounds__(512) void k1_all(
    const float* __restrict__ query, const float* __restrict__ ipw,
    const float* __restrict__ ipb, const float* __restrict__ stw,
    const float* __restrict__ stb, const float* __restrict__ meta,
    u16* __restrict__ u, u16* __restrict__ metaT, float* __restrict__ strat,
    float* __restrict__ wbuf, float* __restrict__ out)
{
  __shared__ __align__(16) char smem[SMEM_BYTES];
  const int bid = blockIdx.x, tid = threadIdx.x;
  if (bid < 32) {
    dev_k1(smem, bid >> 2, (bid >> 1) & 1, bid & 1, query, ipw, ipb, stw, stb, u, strat);
  } else if (bid < 56) {
    dev_meta(smem, bid - 32, meta, metaT);
  } else {
    int zb = bid - 56;   // 16 blocks zero wbuf+lbuf (131,584 f32x4 contiguous)
    float4 z4 = make_float4(0.f, 0.f, 0.f, 0.f);
    float4* z = (float4*)wbuf;
    for (int i = zb * 512 + tid; i < 131584; i += 16 * 512) z[i] = z4;
    if (zb < 4) ((float4*)out)[zb * 512 + tid] = z4;   // out: 2,048 f32x4
  }
}

__global__ __launch_bounds__(512) void k4_sep(
    const float* __restrict__ docs, const float* __restrict__ cw,
    const u16* __restrict__ u, float* __restrict__ wbuf, float* __restrict__ lbuf)
{
  __shared__ __align__(16) char smem[SMEM_BYTES];
  dev_k4(smem, blockIdx.x, blockIdx.y, docs, cw, u, wbuf, lbuf);
}

__global__ __launch_bounds__(512) void k5_sep(
    const float* __restrict__ ipw, const float* __restrict__ ipb,
    const float* __restrict__ opw, const float* __restrict__ opb,
    const u16* __restrict__ metaT, const float* __restrict__ wbuf,
    const float* __restrict__ lbuf, const float* __restrict__ strat,
    float* __restrict__ out)
{
  __shared__ __align__(16) char smem[SMEM_BYTES];
  dev_k5(smem, blockIdx.x & 7, (blockIdx.x >> 3) * 16,
         ipw, ipb, opw, opb, metaT, wbuf, lbuf, strat, out);
}

extern "C" void kernel_launch(void* const* d_in, const int* in_sizes, int n_in,
                              void* d_out, int out_size, void* d_ws, size_t ws_size,
                              hipStream_t stream) {
  const float* query = (const float*)d_in[0];
  const float* docs  = (const float*)d_in[1];
  const float* cw    = (const float*)d_in[2];
  // d_in[3] context_history: unused by the reference
  const float* ipw   = (const float*)d_in[4];
  const float* ipb   = (const float*)d_in[5];
  const float* opw   = (const float*)d_in[6];
  const float* opb   = (const float*)d_in[7];
  const float* stw   = (const float*)d_in[8];
  const float* stb   = (const float*)d_in[9];
  const float* meta  = (const float*)d_in[10];
  float* out = (float*)d_out;

  char* base = (char*)d_ws;
  u16*   u     = (u16*)(base + UB_U);
  float* wbuf  = (float*)(base + UB_W);
  float* lbuf  = (float*)(base + UB_L);
  float* strat = (float*)(base + UB_STRAT);
  u16*   metaT = (u16*)(base + UB_MT);

  k1_all<<<dim3(72), 512, 0, stream>>>(query, ipw, ipb, stw, stb, meta,
                                       u, metaT, strat, wbuf, out);
  k4_sep<<<dim3(NCH_, B_), 512, 0, stream>>>(docs, cw, u, wbuf, lbuf);
  k5_sep<<<dim3(16), 512, 0, stream>>>(ipw, ipb, opw, opb, metaT, wbuf, lbuf, strat, out);
}